// Round 12
// baseline (111.176 us; speedup 1.0000x reference)
//
#include <hip/hip_runtime.h>
#include <hip/hip_bf16.h>

using f32x4  = __attribute__((ext_vector_type(4))) float;
using bf16x8 = __attribute__((ext_vector_type(8))) __bf16;
using u16x8  = __attribute__((ext_vector_type(8))) unsigned short;

#define QSCALE 0.18033688f   // 0.125 * log2(e): scores pre-scaled into exp2 domain

static __device__ __forceinline__ unsigned short f2bf(float f) {
    unsigned u = __builtin_bit_cast(unsigned, f);
    u += 0x7FFF + ((u >> 16) & 1);   // RNE
    return (unsigned short)(u >> 16);
}

static __device__ __forceinline__ float fexp2(float x) {
    float r;
    asm("v_exp_f32 %0, %1" : "=v"(r) : "v"(x));
    return r;
}

static __device__ __forceinline__ void gload_lds16(const unsigned short* g, unsigned short* l) {
    __builtin_amdgcn_global_load_lds(
        (const __attribute__((address_space(1))) unsigned int*)g,
        (__attribute__((address_space(3))) unsigned int*)l, 16, 0, 0);
}

// ---------------------------------------------------------------------------
// Kernel 0: fp32 -> bf16 convert (X q/k/v, W q/k/v).
// ---------------------------------------------------------------------------
__global__ __launch_bounds__(256) void cvt6(
    const float* __restrict__ s0, const float* __restrict__ s1, const float* __restrict__ s2,
    const float* __restrict__ s3, const float* __restrict__ s4, const float* __restrict__ s5,
    unsigned short* __restrict__ d0, unsigned short* __restrict__ d1, unsigned short* __restrict__ d2,
    unsigned short* __restrict__ d3, unsigned short* __restrict__ d4, unsigned short* __restrict__ d5)
{
    const int y = blockIdx.y;
    const float* s = y == 0 ? s0 : y == 1 ? s1 : y == 2 ? s2 : y == 3 ? s3 : y == 4 ? s4 : s5;
    unsigned short* d = y == 0 ? d0 : y == 1 ? d1 : y == 2 ? d2 : y == 3 ? d3 : y == 4 ? d4 : d5;
    const int n = (y < 3) ? 4 * 1024 * 1024 : 1024 * 1024;
    const int stride = gridDim.x * 256 * 8;
    for (int i = (blockIdx.x * 256 + threadIdx.x) * 8; i < n; i += stride) {
        f32x4 a = *(const f32x4*)(s + i);
        f32x4 b = *(const f32x4*)(s + i + 4);
        u16x8 o;
        o[0] = f2bf(a.x); o[1] = f2bf(a.y); o[2] = f2bf(a.z); o[3] = f2bf(a.w);
        o[4] = f2bf(b.x); o[5] = f2bf(b.y); o[6] = f2bf(b.z); o[7] = f2bf(b.w);
        *(u16x8*)(d + i) = o;
    }
}

// ---------------------------------------------------------------------------
// Kernel 1: Y = X @ W^T + bias, bf16 — SINGLE-WAVE blocks, barrier-free.
// 3072 blocks x 64 threads; each block computes one 64x64 output tile.
// Per K-step (BK=32): stage next A+B tile (8x global_load_lds, XOR-pre-
// swizzled source), s_waitcnt vmcnt(8) (next tile stays in flight), 8x
// ds_read_b128 (same XOR -> <=2 lanes/bank), 16 MFMA. No __syncthreads.
// LDS 16 KiB dbuf -> 10 blocks/CU. bid: bm=(local&7)+((local>>7)<<3) keeps
// each A row-panel on one XCD. which = bid>>10; which==0 (Q) xQSCALE.
// ---------------------------------------------------------------------------
__global__ __launch_bounds__(64, 3) void gemm_bt(
    const unsigned short* __restrict__ A0, const unsigned short* __restrict__ A1, const unsigned short* __restrict__ A2,
    const unsigned short* __restrict__ B0, const unsigned short* __restrict__ B1, const unsigned short* __restrict__ B2,
    const float* __restrict__ b0, const float* __restrict__ b1, const float* __restrict__ b2,
    unsigned short* __restrict__ O0, unsigned short* __restrict__ O1, unsigned short* __restrict__ O2)
{
    const int N = 1024, K = 1024;
    const int bid = blockIdx.x;
    const int which = bid >> 10;
    const int local = bid & 1023;
    const unsigned short* A = which == 0 ? A0 : (which == 1 ? A1 : A2);
    const unsigned short* B = which == 0 ? B0 : (which == 1 ? B1 : B2);
    const float* bias = which == 0 ? b0 : (which == 1 ? b1 : b2);
    unsigned short* O = which == 0 ? O0 : (which == 1 ? O1 : O2);

    // XCD-chunked decode: xcd = local&7 owns bm in {xcd, xcd+8, ...}
    const int bm = (local & 7) + ((local >> 7) << 3);   // 0..63
    const int bn = (local >> 3) & 15;                   // 0..15
    const int row0 = bm * 64, col0 = bn * 64;

    __shared__ __align__(16) unsigned short As[2][2048];  // [64 rows][4 chunk slots], slot j holds chunk j^(row&3)
    __shared__ __align__(16) unsigned short Bs[2][2048];

    const int lane = threadIdx.x;
    const int fr = lane & 15;
    const int fq = lane >> 4;

    // staging geometry: issue i covers rows 16i..16i+15
    const int srow = lane >> 2;                    // 0..15
    const int cc   = (lane & 3) ^ (srow & 3);      // swizzled source chunk (row-invariant mod 16)

    f32x4 acc[4][4] = {};

    const unsigned short* Ab = A + (size_t)(row0 + srow) * K + cc * 8;
    const unsigned short* Bb = B + (size_t)(col0 + srow) * K + cc * 8;

    // prologue: stage tile 0 into buf 0
    #pragma unroll
    for (int i = 0; i < 4; ++i) {
        gload_lds16(Ab + (size_t)(16 * i) * K, &As[0][i * 512]);
        gload_lds16(Bb + (size_t)(16 * i) * K, &Bs[0][i * 512]);
    }

    int cur = 0;
    for (int kt = 0; kt < 32; ++kt) {
        const bool stage = (kt + 1 < 32);
        if (stage) {
            const int knext = (kt + 1) * 32;
            #pragma unroll
            for (int i = 0; i < 4; ++i) {
                gload_lds16(Ab + (size_t)(16 * i) * K + knext, &As[cur ^ 1][i * 512]);
                gload_lds16(Bb + (size_t)(16 * i) * K + knext, &Bs[cur ^ 1][i * 512]);
            }
        }

        // wait for current tile; next tile's 8 loads stay in flight
        if (stage) asm volatile("s_waitcnt vmcnt(8)" ::: "memory");
        else       asm volatile("s_waitcnt vmcnt(0)" ::: "memory");
        __builtin_amdgcn_sched_barrier(0);

        bf16x8 af[4], bfr[4];
        #pragma unroll
        for (int m = 0; m < 4; ++m) {
            const int row = m * 16 + fr;
            af[m] = *(const bf16x8*)(&As[cur][row * 32 + ((fq ^ (fr & 3)) * 8)]);
        }
        #pragma unroll
        for (int n = 0; n < 4; ++n) {
            const int row = n * 16 + fr;
            bfr[n] = *(const bf16x8*)(&Bs[cur][row * 32 + ((fq ^ (fr & 3)) * 8)]);
        }

        __builtin_amdgcn_s_setprio(1);
        #pragma unroll
        for (int m = 0; m < 4; ++m)
            #pragma unroll
            for (int n = 0; n < 4; ++n)
                acc[m][n] = __builtin_amdgcn_mfma_f32_16x16x32_bf16(af[m], bfr[n], acc[m][n], 0, 0, 0);
        __builtin_amdgcn_s_setprio(0);

        cur ^= 1;
    }

    const float sc = (which == 0) ? QSCALE : 1.0f;
    #pragma unroll
    for (int n = 0; n < 4; ++n) {
        const int col = col0 + n * 16 + fr;
        const float bv = bias[col];
        #pragma unroll
        for (int m = 0; m < 4; ++m) {
            #pragma unroll
            for (int r = 0; r < 4; ++r) {
                const int row = row0 + m * 16 + fq * 4 + r;
                O[(size_t)row * N + col] = f2bf((acc[m][n][r] + bv) * sc);
            }
        }
    }
}

// ---------------------------------------------------------------------------
// Kernel 1b: V[b*S+s][h*64+dk] -> Vt[(b*16+h)*64+dk][s]. LDS 64x72 tile.
// ---------------------------------------------------------------------------
__global__ __launch_bounds__(256) void vtrans(
    const unsigned short* __restrict__ V, unsigned short* __restrict__ Vt)
{
    const int S = 1024, Dm = 1024;
    const int sb = blockIdx.x;
    const int h = blockIdx.y, b = blockIdx.z;
    __shared__ __align__(16) unsigned short Lt[64][72];
    const int t = threadIdx.x;

    const int sl = t >> 3, dk0 = (t & 7) * 8;
    #pragma unroll
    for (int i = 0; i < 2; ++i) {
        const int s = sl + i * 32;
        u16x8 v = *(const u16x8*)(V + (size_t)(b * S + sb * 64 + s) * Dm + h * 64 + dk0);
        #pragma unroll
        for (int j = 0; j < 8; ++j)
            Lt[dk0 + j][s] = v[j];
    }
    __syncthreads();

    const int dk = t >> 2, scc = (t & 3) * 16;
    const size_t orow = ((size_t)((b * 16 + h) * 64 + dk)) * S + sb * 64;
    *(u16x8*)(Vt + orow + scc)     = *(const u16x8*)(&Lt[dk][scc]);
    *(u16x8*)(Vt + orow + scc + 8) = *(const u16x8*)(&Lt[dk][scc + 8]);
}

// ---------------------------------------------------------------------------
// Kernel 2: causal flash attention. 2048 SINGLE-WAVE blocks (64 threads),
// each owning one 32-row q-block (wave computes 2x 16-row groups). NO
// barriers: wave-private LDS ordered by lgkm/vmcnt. K double-buffered via
// global_load_lds with counted vmcnt (never drained to 0 mid-loop, T4).
// bid encoding keeps XCD locality and complementary per-CU load balance.
// LDS = 16KiB Ks + 4KiB Ps = 20480 B -> 8 blocks/CU (all 2048 co-resident).
// ---------------------------------------------------------------------------
__global__ __launch_bounds__(64, 2) void attn_fwd(
    const unsigned short* __restrict__ Qw, const unsigned short* __restrict__ Kw,
    const unsigned short* __restrict__ Vt, const int* __restrict__ amask,
    float* __restrict__ out)
{
    const int S = 1024, Dm = 1024;
    const int bid = blockIdx.x;
    const int m_  = bid >> 3;              // 0..255
    const int s_  = m_ >> 7;
    const int u_  = m_ & 127;
    const int p_  = u_ >> 3;               // 0..15
    const int bh  = (bid & 7) | ((u_ & 7) << 3);
    const int qb  = s_ ? (31 - p_) : p_;   // 32-row q-block index
    const int b = bh >> 4, h = bh & 15;
    const int lane = threadIdx.x;
    const int fr = lane & 15, fq = lane >> 4;

    __shared__ __align__(16) unsigned short Ks[2][4096];  // [64 rows][8 chunk slots], slot j holds chunk j^(row&7)
    __shared__ __align__(16) unsigned short Ps[32][64];   // XOR-swizzled: [row][col ^ ((row&7)<<3)]

    const size_t kwbase = (size_t)(b * S) * Dm + h * 64;
    const size_t vtbase = (size_t)((b * 16 + h) * 64) * S;

    const int srow = lane >> 3;    // 0..7
    const int schunk = lane & 7;

    const int q0 = qb * 32;
    const int nkt = (qb >> 1) + 1;   // 64-wide k-tiles

    // hoisted att_mask all-ones check
    bool mall;
    {
        const int4* ap = (const int4*)(amask + b * S);
        int acc = -1;
        #pragma unroll
        for (int c = 0; c < 4; ++c) {
            int4 v = ap[lane * 4 + c];
            acc &= (v.x != 0 && v.y != 0 && v.z != 0 && v.w != 0) ? -1 : 0;
        }
        mall = __all(acc != 0);
    }

    // Q fragments: 2 row-groups x 2 k-chunks
    bf16x8 qf[2][2];
    #pragma unroll
    for (int g = 0; g < 2; ++g) {
        const size_t qbp = (size_t)(b * S + q0 + g * 16 + fr) * Dm + h * 64;
        qf[g][0] = *(const bf16x8*)(Qw + qbp + fq * 8);
        qf[g][1] = *(const bf16x8*)(Qw + qbp + 32 + fq * 8);
    }

    f32x4 oacc[2][4] = {};
    float mrow[2][4], lpart[2][4];
    #pragma unroll
    for (int g = 0; g < 2; ++g)
        #pragma unroll
        for (int r = 0; r < 4; ++r) { mrow[g][r] = -3.0e38f; lpart[g][r] = 0.f; }

    // prologue: stage tile 0 into buf 0 (8 x 1KiB issues)
    #pragma unroll
    for (int i = 0; i < 8; ++i) {
        const int r_ = 8 * i + srow;
        const int cc = schunk ^ (r_ & 7);
        gload_lds16(Kw + kwbase + (size_t)r_ * Dm + cc * 8, &Ks[0][i * 512]);
    }

    int cur = 0;
    for (int kt = 0; kt < nkt; ++kt) {
        const int k0 = kt * 64;
        const bool stage = (kt + 1 < nkt);

        // stage next K tile (async; stays in flight across this tile's compute)
        if (stage) {
            #pragma unroll
            for (int i = 0; i < 8; ++i) {
                const int r_ = 8 * i + srow;
                const int cc = schunk ^ (r_ & 7);
                gload_lds16(Kw + kwbase + (size_t)(k0 + 64 + r_) * Dm + cc * 8,
                            &Ks[cur ^ 1][i * 512]);
            }
        }

        // V fragments direct from global (issue early, consumed by PV)
        bf16x8 vb[4][2];
        #pragma unroll
        for (int d = 0; d < 4; ++d)
            #pragma unroll
            for (int kc = 0; kc < 2; ++kc)
                vb[d][kc] = *(const bf16x8*)(Vt + vtbase + (size_t)(d * 16 + fr) * S + k0 + kc * 32 + fq * 8);

        // wait: K(t) staged; K(t+1) 8 + V(t) 8 may remain in flight
        if (stage) asm volatile("s_waitcnt vmcnt(16)" ::: "memory");
        else       asm volatile("s_waitcnt vmcnt(8)"  ::: "memory");
        __builtin_amdgcn_sched_barrier(0);

        // S = Q K^T from swizzled LDS (kb fragments shared by both row-groups)
        f32x4 sfr[2][4];
        __builtin_amdgcn_s_setprio(1);
        #pragma unroll
        for (int nf = 0; nf < 4; ++nf) {
            const int row = nf * 16 + fr;
            const bf16x8 kb0 = *(const bf16x8*)(&Ks[cur][row * 64 + ((fq ^ (row & 7)) * 8)]);
            const bf16x8 kb1 = *(const bf16x8*)(&Ks[cur][row * 64 + (((fq + 4) ^ (row & 7)) * 8)]);
            #pragma unroll
            for (int g = 0; g < 2; ++g) {
                f32x4 z = {};
                z = __builtin_amdgcn_mfma_f32_16x16x32_bf16(qf[g][0], kb0, z, 0, 0, 0);
                z = __builtin_amdgcn_mfma_f32_16x16x32_bf16(qf[g][1], kb1, z, 0, 0, 0);
                sfr[g][nf] = z;
            }
        }
        __builtin_amdgcn_s_setprio(0);

        if (!mall) {
            #pragma unroll
            for (int nf = 0; nf < 4; ++nf) {
                const float pen = (amask[b * S + k0 + nf * 16 + fr] == 0) ? -3.0e38f : 0.f;
                #pragma unroll
                for (int g = 0; g < 2; ++g)
                    #pragma unroll
                    for (int r = 0; r < 4; ++r) sfr[g][nf][r] += pen;
            }
        }
        // causal: only diagonal tile
        if (kt == nkt - 1) {
            #pragma unroll
            for (int nf = 0; nf < 4; ++nf) {
                const int kpos = k0 + nf * 16 + fr;
                #pragma unroll
                for (int g = 0; g < 2; ++g)
                    #pragma unroll
                    for (int r = 0; r < 4; ++r) {
                        const int qr = q0 + g * 16 + fq * 4 + r;
                        if (kpos > qr) sfr[g][nf][r] = -3.0e38f;
                    }
            }
        }

        // defer-max (THR=8 in exp2 domain)
        float plm[2][4];
        float grow = -3.0e38f;
        #pragma unroll
        for (int g = 0; g < 2; ++g)
            #pragma unroll
            for (int r = 0; r < 4; ++r) {
                plm[g][r] = fmaxf(fmaxf(sfr[g][0][r], sfr[g][1][r]),
                                  fmaxf(sfr[g][2][r], sfr[g][3][r]));
                grow = fmaxf(grow, plm[g][r] - mrow[g][r]);
            }
        if (!__all(grow <= 8.0f)) {
            #pragma unroll
            for (int g = 0; g < 2; ++g)
                #pragma unroll
                for (int r = 0; r < 4; ++r) {
                    float v = plm[g][r];
                    v = fmaxf(v, __shfl_xor(v, 1));
                    v = fmaxf(v, __shfl_xor(v, 2));
                    v = fmaxf(v, __shfl_xor(v, 4));
                    v = fmaxf(v, __shfl_xor(v, 8));
                    const float mn = fmaxf(mrow[g][r], v);
                    const float sc = fexp2(mrow[g][r] - mn);
                    mrow[g][r] = mn;
                    lpart[g][r] *= sc;
                    #pragma unroll
                    for (int d = 0; d < 4; ++d) oacc[g][d][r] *= sc;
                }
        }

        // p = exp2(s - m); per-lane partial sums; P -> swizzled LDS (bf16)
        #pragma unroll
        for (int g = 0; g < 2; ++g)
            #pragma unroll
            for (int nf = 0; nf < 4; ++nf)
                #pragma unroll
                for (int r = 0; r < 4; ++r) {
                    const float pv = fexp2(sfr[g][nf][r] - mrow[g][r]);
                    lpart[g][r] += pv;
                    const int rw = g * 16 + fq * 4 + r;
                    const int colx = (nf * 16 + fr) ^ ((rw & 7) << 3);
                    Ps[rw][colx] = f2bf(pv);
                }

        // O += P V (reads apply the same XOR; lgkm ordering is wave-local)
        __builtin_amdgcn_s_setprio(1);
        #pragma unroll
        for (int g = 0; g < 2; ++g) {
            const bf16x8 pa0 = *(const bf16x8*)(&Ps[g * 16 + fr][(fq ^ (fr & 7)) * 8]);
            const bf16x8 pa1 = *(const bf16x8*)(&Ps[g * 16 + fr][((fq + 4) ^ (fr & 7)) * 8]);
            #pragma unroll
            for (int d = 0; d < 4; ++d) {
                oacc[g][d] = __builtin_amdgcn_mfma_f32_16x16x32_bf16(pa0, vb[d][0], oacc[g][d], 0, 0, 0);
                oacc[g][d] = __builtin_amdgcn_mfma_f32_16x16x32_bf16(pa1, vb[d][1], oacc[g][d], 0, 0, 0);
            }
        }
        __builtin_amdgcn_s_setprio(0);

        cur ^= 1;
    }

    // epilogue
    #pragma unroll
    for (int g = 0; g < 2; ++g) {
        float inv[4];
        #pragma unroll
        for (int r = 0; r < 4; ++r) {
            float v = lpart[g][r];
            v += __shfl_xor(v, 1);
            v += __shfl_xor(v, 2);
            v += __shfl_xor(v, 4);
            v += __shfl_xor(v, 8);
            inv[r] = 1.0f / v;
        }
        #pragma unroll
        for (int d = 0; d < 4; ++d)
            #pragma unroll
            for (int r = 0; r < 4; ++r) {
                const int qr = q0 + g * 16 + fq * 4 + r;
                out[(size_t)(b * S + qr) * Dm + h * 64 + d * 16 + fr] = oacc[g][d][r] * inv[r];
            }
    }
}

// ---------------------------------------------------------------------------
extern "C" void kernel_launch(void* const* d_in, const int* in_sizes, int n_in,
                              void* d_out, int out_size, void* d_ws, size_t ws_size,
                              hipStream_t stream)
{
    const float* query = (const float*)d_in[0];
    const float* key_  = (const float*)d_in[1];
    const float* value = (const float*)d_in[2];
    const int*   amask = (const int*)d_in[3];
    const float* Wq = (const float*)d_in[4];
    const float* bq = (const float*)d_in[5];
    const float* Wk = (const float*)d_in[6];
    const float* bk = (const float*)d_in[7];
    const float* Wv = (const float*)d_in[8];
    const float* bv = (const float*)d_in[9];
    float* out = (float*)d_out;

    const size_t MD = (size_t)4096 * 1024;
    const size_t WD = (size_t)1024 * 1024;
    unsigned short* Qw  = (unsigned short*)d_ws;
    unsigned short* Kw  = Qw + MD;
    unsigned short* Vw  = Kw + MD;
    unsigned short* Vtw = Vw + MD;
    unsigned short* Xq  = Vtw + MD;
    unsigned short* Xk  = Xq + MD;
    unsigned short* Xv  = Xk + MD;
    unsigned short* Wqb = Xv + MD;
    unsigned short* Wkb = Wqb + WD;
    unsigned short* Wvb = Wkb + WD;

    hipLaunchKernelGGL(cvt6, dim3(512, 6), dim3(256), 0, stream,
                       query, key_, value, Wq, Wk, Wv,
                       Xq, Xk, Xv, Wqb, Wkb, Wvb);
    hipLaunchKernelGGL(gemm_bt, dim3(3072), dim3(64), 0, stream,
                       Xq, Xk, Xv, Wqb, Wkb, Wvb, bq, bk, bv, Qw, Kw, Vw);
    hipLaunchKernelGGL(vtrans, dim3(16, 16, 4), dim3(256), 0, stream, Vw, Vtw);
    hipLaunchKernelGGL(attn_fwd, dim3(2048), dim3(64), 0, stream,
                       Qw, Kw, Vtw, amask, out);
}

// Round 13
// 101.834 us; speedup vs baseline: 1.0917x; 1.0917x over previous
//
#include <hip/hip_runtime.h>
#include <hip/hip_bf16.h>

using f32x4  = __attribute__((ext_vector_type(4))) float;
using bf16x8 = __attribute__((ext_vector_type(8))) __bf16;
using u16x8  = __attribute__((ext_vector_type(8))) unsigned short;

#define QSCALE 0.18033688f   // 0.125 * log2(e): scores pre-scaled into exp2 domain

static __device__ __forceinline__ unsigned short f2bf(float f) {
    unsigned u = __builtin_bit_cast(unsigned, f);
    u += 0x7FFF + ((u >> 16) & 1);   // RNE
    return (unsigned short)(u >> 16);
}

static __device__ __forceinline__ float fexp2(float x) {
    float r;
    asm("v_exp_f32 %0, %1" : "=v"(r) : "v"(x));
    return r;
}

static __device__ __forceinline__ void gload_lds16(const unsigned short* g, unsigned short* l) {
    __builtin_amdgcn_global_load_lds(
        (const __attribute__((address_space(1))) unsigned int*)g,
        (__attribute__((address_space(3))) unsigned int*)l, 16, 0, 0);
}

// ---------------------------------------------------------------------------
// Kernel 0: fp32 -> bf16 convert (X q/k/v, W q/k/v).
// ---------------------------------------------------------------------------
__global__ __launch_bounds__(256) void cvt6(
    const float* __restrict__ s0, const float* __restrict__ s1, const float* __restrict__ s2,
    const float* __restrict__ s3, const float* __restrict__ s4, const float* __restrict__ s5,
    unsigned short* __restrict__ d0, unsigned short* __restrict__ d1, unsigned short* __restrict__ d2,
    unsigned short* __restrict__ d3, unsigned short* __restrict__ d4, unsigned short* __restrict__ d5)
{
    const int y = blockIdx.y;
    const float* s = y == 0 ? s0 : y == 1 ? s1 : y == 2 ? s2 : y == 3 ? s3 : y == 4 ? s4 : s5;
    unsigned short* d = y == 0 ? d0 : y == 1 ? d1 : y == 2 ? d2 : y == 3 ? d3 : y == 4 ? d4 : d5;
    const int n = (y < 3) ? 4 * 1024 * 1024 : 1024 * 1024;
    const int stride = gridDim.x * 256 * 8;
    for (int i = (blockIdx.x * 256 + threadIdx.x) * 8; i < n; i += stride) {
        f32x4 a = *(const f32x4*)(s + i);
        f32x4 b = *(const f32x4*)(s + i + 4);
        u16x8 o;
        o[0] = f2bf(a.x); o[1] = f2bf(a.y); o[2] = f2bf(a.z); o[3] = f2bf(a.w);
        o[4] = f2bf(b.x); o[5] = f2bf(b.y); o[6] = f2bf(b.z); o[7] = f2bf(b.w);
        *(u16x8*)(d + i) = o;
    }
}

// ---------------------------------------------------------------------------
// Kernel 1 (m97 loop, 64x128 tile, 2-wave blocks): Y = X @ W^T + bias.
// 1536 blocks x 128 threads -> 6 blocks/CU = 6 independent 2-wave barrier
// domains (same per-wave MFMA:ds_read:stage ratio as the proven 128^2 m97
// form). XCD chunking: bid%8 owns bm panels {bid%8 + 8k} -> each A 64-row
// panel lives on exactly one XCD's L2. which = bid>>9; which==0 (Q) xQSCALE.
// ---------------------------------------------------------------------------
__global__ __launch_bounds__(128) void gemm_bt(
    const unsigned short* __restrict__ A0, const unsigned short* __restrict__ A1, const unsigned short* __restrict__ A2,
    const unsigned short* __restrict__ B0, const unsigned short* __restrict__ B1, const unsigned short* __restrict__ B2,
    const float* __restrict__ b0, const float* __restrict__ b1, const float* __restrict__ b2,
    unsigned short* __restrict__ O0, unsigned short* __restrict__ O1, unsigned short* __restrict__ O2)
{
    const int N = 1024, K = 1024;
    const int bid = blockIdx.x;
    const int which = bid >> 9;          // 512 blocks per GEMM
    const int local = bid & 511;
    const unsigned short* A = which == 0 ? A0 : (which == 1 ? A1 : A2);
    const unsigned short* B = which == 0 ? B0 : (which == 1 ? B1 : B2);
    const float* bias = which == 0 ? b0 : (which == 1 ? b1 : b2);
    unsigned short* O = which == 0 ? O0 : (which == 1 ? O1 : O2);

    // XCD-chunked decode: xcd = local&7 owns bm in {xcd, xcd+8, ...}
    const int bm = (local & 7) + ((local >> 6) << 3);   // 0..63
    const int bn = (local >> 3) & 7;                    // 0..7
    const int row0 = bm * 64, col0 = bn * 128;

    __shared__ __align__(16) unsigned short As[64 * 32];    // 4 KiB
    __shared__ __align__(16) unsigned short Bs[128 * 32];   // 8 KiB

    const int t = threadIdx.x;
    const int lane = t & 63;
    const int wave = t >> 6;
    const int fr = lane & 15;
    const int fq = lane >> 4;
    const int srow = lane >> 2;          // 0..15
    const int sc   = (lane & 3) * 8;     // u16 chunk offset

    f32x4 acc[4][4] = {};

    for (int k0 = 0; k0 < K; k0 += 32) {
        // A: wave w stages rows 32w..32w+31 (2 issues x 1 KiB)
        #pragma unroll
        for (int i = 0; i < 2; ++i) {
            const int rbase = wave * 32 + 16 * i;
            gload_lds16(A + (size_t)(row0 + rbase + srow) * K + k0 + sc, &As[rbase * 32]);
        }
        // B: wave w stages rows 64w..64w+63 (4 issues x 1 KiB)
        #pragma unroll
        for (int j = 0; j < 4; ++j) {
            const int rbase = wave * 64 + 16 * j;
            gload_lds16(B + (size_t)(col0 + rbase + srow) * K + k0 + sc, &Bs[rbase * 32]);
        }
        __syncthreads();

        bf16x8 af[4], bfr[4];
        #pragma unroll
        for (int m = 0; m < 4; ++m)
            af[m] = *(const bf16x8*)(&As[(m * 16 + fr) * 32 + fq * 8]);
        #pragma unroll
        for (int n = 0; n < 4; ++n)
            bfr[n] = *(const bf16x8*)(&Bs[(wave * 64 + n * 16 + fr) * 32 + fq * 8]);
        #pragma unroll
        for (int m = 0; m < 4; ++m)
            #pragma unroll
            for (int n = 0; n < 4; ++n)
                acc[m][n] = __builtin_amdgcn_mfma_f32_16x16x32_bf16(af[m], bfr[n], acc[m][n], 0, 0, 0);
        __syncthreads();
    }

    const float sc2 = (which == 0) ? QSCALE : 1.0f;
    #pragma unroll
    for (int n = 0; n < 4; ++n) {
        const int col = col0 + wave * 64 + n * 16 + fr;
        const float bv = bias[col];
        #pragma unroll
        for (int m = 0; m < 4; ++m) {
            #pragma unroll
            for (int r = 0; r < 4; ++r) {
                const int row = row0 + m * 16 + fq * 4 + r;
                O[(size_t)row * N + col] = f2bf((acc[m][n][r] + bv) * sc2);
            }
        }
    }
}

// ---------------------------------------------------------------------------
// Kernel 1b: V[b*S+s][h*64+dk] -> Vt[(b*16+h)*64+dk][s]. LDS 64x72 tile.
// ---------------------------------------------------------------------------
__global__ __launch_bounds__(256) void vtrans(
    const unsigned short* __restrict__ V, unsigned short* __restrict__ Vt)
{
    const int S = 1024, Dm = 1024;
    const int sb = blockIdx.x;
    const int h = blockIdx.y, b = blockIdx.z;
    __shared__ __align__(16) unsigned short Lt[64][72];
    const int t = threadIdx.x;

    const int sl = t >> 3, dk0 = (t & 7) * 8;
    #pragma unroll
    for (int i = 0; i < 2; ++i) {
        const int s = sl + i * 32;
        u16x8 v = *(const u16x8*)(V + (size_t)(b * S + sb * 64 + s) * Dm + h * 64 + dk0);
        #pragma unroll
        for (int j = 0; j < 8; ++j)
            Lt[dk0 + j][s] = v[j];
    }
    __syncthreads();

    const int dk = t >> 2, scc = (t & 3) * 16;
    const size_t orow = ((size_t)((b * 16 + h) * 64 + dk)) * S + sb * 64;
    *(u16x8*)(Vt + orow + scc)     = *(const u16x8*)(&Lt[dk][scc]);
    *(u16x8*)(Vt + orow + scc + 8) = *(const u16x8*)(&Lt[dk][scc + 8]);
}

// ---------------------------------------------------------------------------
// Kernel 2: causal flash attention. 2048 SINGLE-WAVE blocks (64 threads),
// each owning one 32-row q-block (wave computes 2x 16-row groups). NO
// barriers: wave-private LDS ordered by lgkm/vmcnt. K double-buffered via
// global_load_lds with counted vmcnt (never drained to 0 mid-loop, T4).
// bid encoding keeps XCD locality and complementary per-CU load balance.
// LDS = 16KiB Ks + 4KiB Ps = 20480 B -> 8 blocks/CU (all 2048 co-resident).
// ---------------------------------------------------------------------------
__global__ __launch_bounds__(64, 2) void attn_fwd(
    const unsigned short* __restrict__ Qw, const unsigned short* __restrict__ Kw,
    const unsigned short* __restrict__ Vt, const int* __restrict__ amask,
    float* __restrict__ out)
{
    const int S = 1024, Dm = 1024;
    const int bid = blockIdx.x;
    const int m_  = bid >> 3;              // 0..255
    const int s_  = m_ >> 7;
    const int u_  = m_ & 127;
    const int p_  = u_ >> 3;               // 0..15
    const int bh  = (bid & 7) | ((u_ & 7) << 3);
    const int qb  = s_ ? (31 - p_) : p_;   // 32-row q-block index
    const int b = bh >> 4, h = bh & 15;
    const int lane = threadIdx.x;
    const int fr = lane & 15, fq = lane >> 4;

    __shared__ __align__(16) unsigned short Ks[2][4096];  // [64 rows][8 chunk slots], slot j holds chunk j^(row&7)
    __shared__ __align__(16) unsigned short Ps[32][64];   // XOR-swizzled: [row][col ^ ((row&7)<<3)]

    const size_t kwbase = (size_t)(b * S) * Dm + h * 64;
    const size_t vtbase = (size_t)((b * 16 + h) * 64) * S;

    const int srow = lane >> 3;    // 0..7
    const int schunk = lane & 7;

    const int q0 = qb * 32;
    const int nkt = (qb >> 1) + 1;   // 64-wide k-tiles

    // hoisted att_mask all-ones check
    bool mall;
    {
        const int4* ap = (const int4*)(amask + b * S);
        int acc = -1;
        #pragma unroll
        for (int c = 0; c < 4; ++c) {
            int4 v = ap[lane * 4 + c];
            acc &= (v.x != 0 && v.y != 0 && v.z != 0 && v.w != 0) ? -1 : 0;
        }
        mall = __all(acc != 0);
    }

    // Q fragments: 2 row-groups x 2 k-chunks
    bf16x8 qf[2][2];
    #pragma unroll
    for (int g = 0; g < 2; ++g) {
        const size_t qbp = (size_t)(b * S + q0 + g * 16 + fr) * Dm + h * 64;
        qf[g][0] = *(const bf16x8*)(Qw + qbp + fq * 8);
        qf[g][1] = *(const bf16x8*)(Qw + qbp + 32 + fq * 8);
    }

    f32x4 oacc[2][4] = {};
    float mrow[2][4], lpart[2][4];
    #pragma unroll
    for (int g = 0; g < 2; ++g)
        #pragma unroll
        for (int r = 0; r < 4; ++r) { mrow[g][r] = -3.0e38f; lpart[g][r] = 0.f; }

    // prologue: stage tile 0 into buf 0 (8 x 1KiB issues)
    #pragma unroll
    for (int i = 0; i < 8; ++i) {
        const int r_ = 8 * i + srow;
        const int cc = schunk ^ (r_ & 7);
        gload_lds16(Kw + kwbase + (size_t)r_ * Dm + cc * 8, &Ks[0][i * 512]);
    }

    int cur = 0;
    for (int kt = 0; kt < nkt; ++kt) {
        const int k0 = kt * 64;
        const bool stage = (kt + 1 < nkt);

        // stage next K tile (async; stays in flight across this tile's compute)
        if (stage) {
            #pragma unroll
            for (int i = 0; i < 8; ++i) {
                const int r_ = 8 * i + srow;
                const int cc = schunk ^ (r_ & 7);
                gload_lds16(Kw + kwbase + (size_t)(k0 + 64 + r_) * Dm + cc * 8,
                            &Ks[cur ^ 1][i * 512]);
            }
        }

        // V fragments direct from global (issue early, consumed by PV)
        bf16x8 vb[4][2];
        #pragma unroll
        for (int d = 0; d < 4; ++d)
            #pragma unroll
            for (int kc = 0; kc < 2; ++kc)
                vb[d][kc] = *(const bf16x8*)(Vt + vtbase + (size_t)(d * 16 + fr) * S + k0 + kc * 32 + fq * 8);

        // wait: K(t) staged; K(t+1) 8 + V(t) 8 may remain in flight
        if (stage) asm volatile("s_waitcnt vmcnt(16)" ::: "memory");
        else       asm volatile("s_waitcnt vmcnt(8)"  ::: "memory");
        __builtin_amdgcn_sched_barrier(0);

        // S = Q K^T from swizzled LDS (kb fragments shared by both row-groups)
        f32x4 sfr[2][4];
        __builtin_amdgcn_s_setprio(1);
        #pragma unroll
        for (int nf = 0; nf < 4; ++nf) {
            const int row = nf * 16 + fr;
            const bf16x8 kb0 = *(const bf16x8*)(&Ks[cur][row * 64 + ((fq ^ (row & 7)) * 8)]);
            const bf16x8 kb1 = *(const bf16x8*)(&Ks[cur][row * 64 + (((fq + 4) ^ (row & 7)) * 8)]);
            #pragma unroll
            for (int g = 0; g < 2; ++g) {
                f32x4 z = {};
                z = __builtin_amdgcn_mfma_f32_16x16x32_bf16(qf[g][0], kb0, z, 0, 0, 0);
                z = __builtin_amdgcn_mfma_f32_16x16x32_bf16(qf[g][1], kb1, z, 0, 0, 0);
                sfr[g][nf] = z;
            }
        }
        __builtin_amdgcn_s_setprio(0);

        if (!mall) {
            #pragma unroll
            for (int nf = 0; nf < 4; ++nf) {
                const float pen = (amask[b * S + k0 + nf * 16 + fr] == 0) ? -3.0e38f : 0.f;
                #pragma unroll
                for (int g = 0; g < 2; ++g)
                    #pragma unroll
                    for (int r = 0; r < 4; ++r) sfr[g][nf][r] += pen;
            }
        }
        // causal: only diagonal tile
        if (kt == nkt - 1) {
            #pragma unroll
            for (int nf = 0; nf < 4; ++nf) {
                const int kpos = k0 + nf * 16 + fr;
                #pragma unroll
                for (int g = 0; g < 2; ++g)
                    #pragma unroll
                    for (int r = 0; r < 4; ++r) {
                        const int qr = q0 + g * 16 + fq * 4 + r;
                        if (kpos > qr) sfr[g][nf][r] = -3.0e38f;
                    }
            }
        }

        // defer-max (THR=8 in exp2 domain)
        float plm[2][4];
        float grow = -3.0e38f;
        #pragma unroll
        for (int g = 0; g < 2; ++g)
            #pragma unroll
            for (int r = 0; r < 4; ++r) {
                plm[g][r] = fmaxf(fmaxf(sfr[g][0][r], sfr[g][1][r]),
                                  fmaxf(sfr[g][2][r], sfr[g][3][r]));
                grow = fmaxf(grow, plm[g][r] - mrow[g][r]);
            }
        if (!__all(grow <= 8.0f)) {
            #pragma unroll
            for (int g = 0; g < 2; ++g)
                #pragma unroll
                for (int r = 0; r < 4; ++r) {
                    float v = plm[g][r];
                    v = fmaxf(v, __shfl_xor(v, 1));
                    v = fmaxf(v, __shfl_xor(v, 2));
                    v = fmaxf(v, __shfl_xor(v, 4));
                    v = fmaxf(v, __shfl_xor(v, 8));
                    const float mn = fmaxf(mrow[g][r], v);
                    const float sc = fexp2(mrow[g][r] - mn);
                    mrow[g][r] = mn;
                    lpart[g][r] *= sc;
                    #pragma unroll
                    for (int d = 0; d < 4; ++d) oacc[g][d][r] *= sc;
                }
        }

        // p = exp2(s - m); per-lane partial sums; P -> swizzled LDS (bf16)
        #pragma unroll
        for (int g = 0; g < 2; ++g)
            #pragma unroll
            for (int nf = 0; nf < 4; ++nf)
                #pragma unroll
                for (int r = 0; r < 4; ++r) {
                    const float pv = fexp2(sfr[g][nf][r] - mrow[g][r]);
                    lpart[g][r] += pv;
                    const int rw = g * 16 + fq * 4 + r;
                    const int colx = (nf * 16 + fr) ^ ((rw & 7) << 3);
                    Ps[rw][colx] = f2bf(pv);
                }

        // O += P V (reads apply the same XOR; lgkm ordering is wave-local)
        __builtin_amdgcn_s_setprio(1);
        #pragma unroll
        for (int g = 0; g < 2; ++g) {
            const bf16x8 pa0 = *(const bf16x8*)(&Ps[g * 16 + fr][(fq ^ (fr & 7)) * 8]);
            const bf16x8 pa1 = *(const bf16x8*)(&Ps[g * 16 + fr][((fq + 4) ^ (fr & 7)) * 8]);
            #pragma unroll
            for (int d = 0; d < 4; ++d) {
                oacc[g][d] = __builtin_amdgcn_mfma_f32_16x16x32_bf16(pa0, vb[d][0], oacc[g][d], 0, 0, 0);
                oacc[g][d] = __builtin_amdgcn_mfma_f32_16x16x32_bf16(pa1, vb[d][1], oacc[g][d], 0, 0, 0);
            }
        }
        __builtin_amdgcn_s_setprio(0);

        cur ^= 1;
    }

    // epilogue
    #pragma unroll
    for (int g = 0; g < 2; ++g) {
        float inv[4];
        #pragma unroll
        for (int r = 0; r < 4; ++r) {
            float v = lpart[g][r];
            v += __shfl_xor(v, 1);
            v += __shfl_xor(v, 2);
            v += __shfl_xor(v, 4);
            v += __shfl_xor(v, 8);
            inv[r] = 1.0f / v;
        }
        #pragma unroll
        for (int d = 0; d < 4; ++d)
            #pragma unroll
            for (int r = 0; r < 4; ++r) {
                const int qr = q0 + g * 16 + fq * 4 + r;
                out[(size_t)(b * S + qr) * Dm + h * 64 + d * 16 + fr] = oacc[g][d][r] * inv[r];
            }
    }
}

// ---------------------------------------------------------------------------
extern "C" void kernel_launch(void* const* d_in, const int* in_sizes, int n_in,
                              void* d_out, int out_size, void* d_ws, size_t ws_size,
                              hipStream_t stream)
{
    const float* query = (const float*)d_in[0];
    const float* key_  = (const float*)d_in[1];
    const float* value = (const float*)d_in[2];
    const int*   amask = (const int*)d_in[3];
    const float* Wq = (const float*)d_in[4];
    const float* bq = (const float*)d_in[5];
    const float* Wk = (const float*)d_in[6];
    const float* bk = (const float*)d_in[7];
    const float* Wv = (const float*)d_in[8];
    const float* bv = (const float*)d_in[9];
    float* out = (float*)d_out;

    const size_t MD = (size_t)4096 * 1024;
    const size_t WD = (size_t)1024 * 1024;
    unsigned short* Qw  = (unsigned short*)d_ws;
    unsigned short* Kw  = Qw + MD;
    unsigned short* Vw  = Kw + MD;
    unsigned short* Vtw = Vw + MD;
    unsigned short* Xq  = Vtw + MD;
    unsigned short* Xk  = Xq + MD;
    unsigned short* Xv  = Xk + MD;
    unsigned short* Wqb = Xv + MD;
    unsigned short* Wkb = Wqb + WD;
    unsigned short* Wvb = Wkb + WD;

    hipLaunchKernelGGL(cvt6, dim3(512, 6), dim3(256), 0, stream,
                       query, key_, value, Wq, Wk, Wv,
                       Xq, Xk, Xv, Wqb, Wkb, Wvb);
    hipLaunchKernelGGL(gemm_bt, dim3(1536), dim3(128), 0, stream,
                       Xq, Xk, Xv, Wqb, Wkb, Wvb, bq, bk, bv, Qw, Kw, Vw);
    hipLaunchKernelGGL(vtrans, dim3(16, 16, 4), dim3(256), 0, stream, Vw, Vtw);
    hipLaunchKernelGGL(attn_fwd, dim3(2048), dim3(64), 0, stream,
                       Qw, Kw, Vtw, amask, out);
}